// Round 7
// baseline (17412.238 us; speedup 1.0000x reference)
//
#include <hip/hip_runtime.h>
#include <math.h>

typedef unsigned int uint;

#define T_STEPS 8192
#define R_CAP 10
#define K1_CAP 32
#define K0_CAP 6

// ===========================================================================
// prep_extract: dense -> raw CSC (capped, zero-padded). 4 tasks x 1024 cols.
// ===========================================================================
__global__ __launch_bounds__(256) void prep_extract(
    const float* __restrict__ k0w, const float* __restrict__ r0w,
    const float* __restrict__ r1w, const float* __restrict__ k1w,
    float* __restrict__ r0vr, uint* __restrict__ r0ur, float* __restrict__ d0r,
    float* __restrict__ r1vr, uint* __restrict__ r1ur, float* __restrict__ d1r,
    float* __restrict__ k1vr, uint* __restrict__ k1ur, int* __restrict__ c1r,
    float* __restrict__ k0vr, uint* __restrict__ k0ur, int* __restrict__ c0r)
{
    int tid = blockIdx.x * 256 + threadIdx.x;
    int task = tid >> 10, j = tid & 1023;

    if (task <= 1) {
        const float* W = task ? r1w : r0w;
        float* vr = task ? r1vr : r0vr;
        uint*  ur = task ? r1ur : r0ur;
        float* dr = task ? d1r  : d0r;
        float diag = 0.f; int c = 0;
#pragma unroll 4
        for (int i = 0; i < 1024; ++i) {
            float v = W[i * 1024 + j];
            if (i == j) diag = v;
            else if (v != 0.f && c < R_CAP) {
                vr[j * R_CAP + c] = v; ur[j * R_CAP + c] = (uint)i; ++c;
            }
        }
        for (; c < R_CAP; ++c) { vr[j * R_CAP + c] = 0.f; ur[j * R_CAP + c] = 0u; }
        dr[j] = diag;
    } else if (task == 2) {
        int c = 0;
#pragma unroll 4
        for (int i = 0; i < 1024; ++i) {
            float v = k1w[i * 1024 + j];
            if (v != 0.f && c < K1_CAP) {
                k1vr[j * K1_CAP + c] = v; k1ur[j * K1_CAP + c] = (uint)i; ++c;
            }
        }
        c1r[j] = c;
        for (int q = c; q < K1_CAP; ++q) { k1vr[j * K1_CAP + q] = 0.f; k1ur[j * K1_CAP + q] = 0u; }
    } else {
        int c = 0;
        for (int i = 0; i < 32; ++i) {
            float v = k0w[i * 1024 + j];
            if (v != 0.f && c < K0_CAP) {
                k0vr[j * K0_CAP + c] = v; k0ur[j * K0_CAP + c] = (uint)i; ++c;
            }
        }
        c0r[j] = c;
        for (int q = c; q < K0_CAP; ++q) { k0vr[j * K0_CAP + q] = 0.f; k0ur[j * K0_CAP + q] = 0u; }
    }
}

// ===========================================================================
// prep_slots: module 0 = IDENTITY layout; module 1 = nnz-rank sorted slots.
// Addresses RELATIVE; LDS map: h0@0/4096, h1@8192/12288, u@16384.
// ===========================================================================
__global__ __launch_bounds__(1024) void prep_slots(
    const float* __restrict__ r0vr, const uint* __restrict__ r0ur,
    const float* __restrict__ r1vr, const uint* __restrict__ r1ur,
    const float* __restrict__ k1vr, const uint* __restrict__ k1ur, const int* __restrict__ c1r,
    const float* __restrict__ k0vr, const uint* __restrict__ k0ur, const int* __restrict__ c0r,
    uint* __restrict__ Gr0a, float* __restrict__ Gr0v, int* __restrict__ Gcr0,
    uint* __restrict__ Gr1a, float* __restrict__ Gr1v, int* __restrict__ Gcr1,
    uint* __restrict__ Gk1a, float* __restrict__ Gk1v, int* __restrict__ Fc1,
    uint* __restrict__ Gk0a, float* __restrict__ Gk0v, int* __restrict__ Fc0,
    int* __restrict__ Fu1, int* __restrict__ Linv1)
{
    __shared__ int lc1[1024];
    __shared__ unsigned short sl1[1024];   // unit -> module-1 slot
    const int j = threadIdx.x;
    const int c1j = c1r[j], c0j = c0r[j];
    lc1[j] = c1j;
    __syncthreads();
    int s1 = 0;
#pragma unroll 4
    for (int i = 0; i < 1024; ++i) {
        int a = lc1[i]; s1 += (a < c1j) || (a == c1j && i < j);
    }
    sl1[j] = (unsigned short)s1;
    __syncthreads();

    {   // module 0, identity at j
        int n = 0;
        for (int k = 0; k < R_CAP; ++k) {
            float v = r0vr[j * R_CAP + k];
            uint  u = r0ur[j * R_CAP + k];
            Gr0v[j * R_CAP + k] = v;
            Gr0a[j * R_CAP + k] = (v != 0.f) ? (u << 2) : 0u;
            if (v != 0.f) n = k + 1;
        }
        Gcr0[j] = n;
        for (int k = 0; k < K0_CAP; ++k) {
            Gk0v[j * K0_CAP + k] = k0vr[j * K0_CAP + k];
            Gk0a[j * K0_CAP + k] = (k < c0j) ? (k0ur[j * K0_CAP + k] << 2) : 0u;
        }
        Fc0[j] = c0j;
    }
    {   // module 1, at slot s1; k1 targets h0 (identity) -> u<<2
        int n = 0;
        for (int k = 0; k < R_CAP; ++k) {
            float v = r1vr[j * R_CAP + k];
            uint  u = r1ur[j * R_CAP + k];
            Gr1v[s1 * R_CAP + k] = v;
            Gr1a[s1 * R_CAP + k] = (v != 0.f) ? (8192u + ((uint)sl1[u] << 2)) : 8192u;
            if (v != 0.f) n = k + 1;
        }
        Gcr1[s1] = n;
        for (int k = 0; k < K1_CAP; ++k) {
            Gk1v[s1 * K1_CAP + k] = k1vr[j * K1_CAP + k];
            Gk1a[s1 * K1_CAP + k] = (k < c1j) ? (k1ur[j * K1_CAP + k] << 2) : 0u;
        }
        Fc1[s1] = c1j; Fu1[s1] = j;
    }
    Linv1[j] = s1;
}

// ===========================================================================
// prep_greedy: cross-lane bank coloring, capacity 1 per (half,bank) pool.
// Reorders entries within a column only -> semantically neutral.
// ===========================================================================
__global__ __launch_bounds__(256) void prep_greedy(
    const uint* __restrict__ Gr0a, const float* __restrict__ Gr0v, const int* __restrict__ Gcr0,
    const uint* __restrict__ Gr1a, const float* __restrict__ Gr1v, const int* __restrict__ Gcr1,
    const uint* __restrict__ Gk1a, const float* __restrict__ Gk1v, const int* __restrict__ Fc1,
    const uint* __restrict__ Gk0a, const float* __restrict__ Gk0v, const int* __restrict__ Fc0,
    float* __restrict__ Fr0v, uint* __restrict__ Fr0a,
    float* __restrict__ Fr1v, uint* __restrict__ Fr1a,
    float* __restrict__ Fk1v, uint* __restrict__ Fk1a,
    float* __restrict__ Fk0v, uint* __restrict__ Fk0a)
{
    __shared__ uint  ea[4][64][32];
    __shared__ float ev[4][64][32];
    __shared__ int   bl[4][64];
    const int wv   = threadIdx.x >> 6;
    const int lane = threadIdx.x & 63;
    const int half = (lane >> 5) * 32;
    const int gw   = blockIdx.x * 4 + wv;
    const int task = gw >> 4;
    const int col  = (gw & 15) * 64 + lane;

    const uint* ga; const float* gv; const int* gc; int cap;
    float* fv; uint* fa;
    if (task == 0)      { ga = Gr0a; gv = Gr0v; gc = Gcr0; cap = R_CAP;  fv = Fr0v; fa = Fr0a; }
    else if (task == 1) { ga = Gr1a; gv = Gr1v; gc = Gcr1; cap = R_CAP;  fv = Fr1v; fa = Fr1a; }
    else if (task == 2) { ga = Gk1a; gv = Gk1v; gc = Fc1;  cap = K1_CAP; fv = Fk1v; fa = Fk1a; }
    else                { ga = Gk0a; gv = Gk0v; gc = Fc0;  cap = K0_CAP; fv = Fk0v; fa = Fk0a; }

    const int cnt = gc[col];
    for (int s = 0; s < cap; ++s) {
        ea[wv][lane][s] = ga[col * cap + s];
        ev[wv][lane][s] = gv[col * cap + s];
    }
    __syncthreads();

    for (int slot = 0; slot < 32; ++slot) {
        bl[wv][lane] = 0;
        __syncthreads();
        int pick = -1;
        const bool active = (slot < cap) && (slot < cnt);
        for (int rnd = 0; rnd < 4; ++rnd) {
            if (active && pick < 0) {
                int best = slot, bload = 1 << 30;
                for (int e = slot; e < cnt; ++e) {
                    int b  = (int)((ea[wv][lane][e] >> 2) & 31u);
                    int ld = bl[wv][half + b];
                    if (ld < bload) { bload = ld; best = e; }
                }
                int bb = (int)((ea[wv][lane][best] >> 2) & 31u);
                if (rnd == 3) {
                    atomicAdd(&bl[wv][half + bb], 1); pick = best;
                } else {
                    int old = atomicAdd(&bl[wv][half + bb], 1);
                    if (old >= 1) atomicSub(&bl[wv][half + bb], 1);
                    else pick = best;
                }
            }
            __syncthreads();
        }
        if (active && pick > slot) {
            uint  ta = ea[wv][lane][slot]; ea[wv][lane][slot] = ea[wv][lane][pick]; ea[wv][lane][pick] = ta;
            float tv = ev[wv][lane][slot]; ev[wv][lane][slot] = ev[wv][lane][pick]; ev[wv][lane][pick] = tv;
        }
        __syncthreads();
    }

    for (int s = 0; s < cap; ++s) fv[col * cap + s] = ev[wv][lane][s];
    for (int p = 0; p < cap / 2; ++p)
        fa[col * (cap / 2) + p] = (ea[wv][lane][2 * p] & 0xffffu) | (ea[wv][lane][2 * p + 1] << 16);
}

// ---------------------------------------------------------------------------
__device__ __forceinline__ float fast_tanh(float x) {
    float ax = fabsf(x);
    float e  = __expf(-2.0f * ax);
    float r  = __builtin_amdgcn_rcpf(1.0f + e);
    float t  = (1.0f - e) * r;
    return copysignf(t, x);
}

#define LD(A) (*(const float*)(smem + (A)))

// Soft barrier: drain LDS ops only; global stores stay in flight (nobody
// reads `out`), so their completion latency never hits the critical path.
#define SOFTBAR do {                                                           \
    asm volatile("s_waitcnt lgkmcnt(0)" ::: "memory");                         \
    __builtin_amdgcn_sched_barrier(0);                                         \
    __builtin_amdgcn_s_barrier();                                              \
    __builtin_amdgcn_sched_barrier(0);                                         \
  } while (0)

// Skewed iteration i (parity P): computes h0(i) [DO0] and h1(i-1) [DO1] from
// the SAME barriered buffers (h0(i-1)@hbuf0[P], h1(i-2)@hbuf1[P], u[i]) --
// both gather bursts issue together, one latency window, one barrier.
// DOG: gather h1(i-2) for unit j from hbuf1[P] and store out (deferred by 2).
#define ITER(P, DO0, DO1, DOG, UOFF)                                           \
  {                                                                            \
    float g1v = 0.f;                                                           \
    if (DOG) g1v = LD(8192u + (P) * 4096u + l1off);                            \
    if (DO0) {                                                                 \
      float xa = __builtin_fmaf(d0, h0j, b0), xb = 0.f, xc = 0.f, xd = 0.f;    \
      {                                                                        \
        uint p0 = r0a[0], p1 = r0a[1], p2 = r0a[2], p3 = r0a[3], p4 = r0a[4];  \
        xa += r0v[0] * LD((p0 & 0xffffu) + (P) * 4096u);                       \
        xb += r0v[1] * LD((p0 >> 16)     + (P) * 4096u);                       \
        xc += r0v[2] * LD((p1 & 0xffffu) + (P) * 4096u);                       \
        xd += r0v[3] * LD((p1 >> 16)     + (P) * 4096u);                       \
        xa += r0v[4] * LD((p2 & 0xffffu) + (P) * 4096u);                       \
        xb += r0v[5] * LD((p2 >> 16)     + (P) * 4096u);                       \
        xc += r0v[6] * LD((p3 & 0xffffu) + (P) * 4096u);                       \
        xd += r0v[7] * LD((p3 >> 16)     + (P) * 4096u);                       \
        xa += r0v[8] * LD((p4 & 0xffffu) + (P) * 4096u);                       \
        xb += r0v[9] * LD((p4 >> 16)     + (P) * 4096u);                       \
      }                                                                        \
      _Pragma("unroll")                                                        \
      for (int kc = 0; kc < K0_CAP; kc += 2) {                                 \
        if (kc < k0m) {                                                        \
          uint pr = k0a[kc >> 1];                                              \
          xc += k0v[kc]     * LD((pr & 0xffffu) + (UOFF));                     \
          xd += k0v[kc + 1] * LD((pr >> 16)     + (UOFF));                     \
        }                                                                      \
      }                                                                        \
      float o0  = fast_tanh((xa + xb) + (xc + xd));                            \
      float h0n = 0.5f * (h0j + o0);                                           \
      ((float*)(smem + (1 - (P)) * 4096u))[j] = h0n;                           \
      *o0p = h0n; o0p += 2048;                                                 \
      h0j = h0n;                                                               \
    }                                                                          \
    if (DOG) { *o1p = g1v; o1p += 2048; }                                      \
    if (DO1) {                                                                 \
      float ya = __builtin_fmaf(d1, h1j, b1), yb = 0.f, yc = 0.f, yd = 0.f;    \
      _Pragma("unroll")                                                        \
      for (int kc = 0; kc < K1_CAP; kc += 4) {                                 \
        if (kc < k1m) {                                                        \
          uint pa = k1a[kc >> 1], pb = k1a[(kc >> 1) + 1];                     \
          ya += k1v[kc]     * LD((pa & 0xffffu) + (P) * 4096u);                \
          yb += k1v[kc + 1] * LD((pa >> 16)     + (P) * 4096u);                \
          yc += k1v[kc + 2] * LD((pb & 0xffffu) + (P) * 4096u);                \
          yd += k1v[kc + 3] * LD((pb >> 16)     + (P) * 4096u);                \
        }                                                                      \
      }                                                                        \
      {                                                                        \
        uint p0 = r1a[0], p1 = r1a[1], p2 = r1a[2], p3 = r1a[3], p4 = r1a[4];  \
        ya += r1v[0] * LD((p0 & 0xffffu) + (P) * 4096u);                       \
        yb += r1v[1] * LD((p0 >> 16)     + (P) * 4096u);                       \
        yc += r1v[2] * LD((p1 & 0xffffu) + (P) * 4096u);                       \
        yd += r1v[3] * LD((p1 >> 16)     + (P) * 4096u);                       \
        ya += r1v[4] * LD((p2 & 0xffffu) + (P) * 4096u);                       \
        yb += r1v[5] * LD((p2 >> 16)     + (P) * 4096u);                       \
        yc += r1v[6] * LD((p3 & 0xffffu) + (P) * 4096u);                       \
        yd += r1v[7] * LD((p3 >> 16)     + (P) * 4096u);                       \
        ya += r1v[8] * LD((p4 & 0xffffu) + (P) * 4096u);                       \
        yb += r1v[9] * LD((p4 >> 16)     + (P) * 4096u);                       \
      }                                                                        \
      float o1  = fast_tanh((ya + yb) + (yc + yd));                            \
      float h1n = 0.5f * (h1j + o1);                                           \
      ((float*)(smem + 8192u + (1 - (P)) * 4096u))[j] = h1n;                   \
      h1j = h1n;                                                               \
    }                                                                          \
    SOFTBAR;                                                                   \
  }

#define STAGE(TT)                                                              \
  {                                                                            \
    ((float*)(smem + 16384))[j]        = u[(TT) * 32 + j];                     \
    ((float*)(smem + 16384))[1024 + j] = u[(TT) * 32 + 1024 + j];              \
    SOFTBAR;                                                                   \
  }

// ===========================================================================
// Persistent single-workgroup scan, module-1 skewed by one step.
// NOTE: r1a entries already contain the +8192 h1 base; k1a/r0a are h0-relative.
// ===========================================================================
__global__ __launch_bounds__(1024, 4) void reservoir_main(
    const float* __restrict__ u,
    const float* __restrict__ bias0, const float* __restrict__ bias1,
    const float* __restrict__ d0r, const float* __restrict__ d1r,
    const float* __restrict__ Fr0v, const uint* __restrict__ Fr0a,
    const float* __restrict__ Fr1v, const uint* __restrict__ Fr1a,
    const float* __restrict__ Fk1v, const uint* __restrict__ Fk1a,
    const float* __restrict__ Fk0v, const uint* __restrict__ Fk0a,
    const int* __restrict__ Fc1, const int* __restrict__ Fc0,
    const int* __restrict__ Fu1, const int* __restrict__ Linv1,
    float* __restrict__ out)
{
    __shared__ __align__(16) char smem[24576];
    const int j = threadIdx.x;

    float r0v[R_CAP], r1v[R_CAP], k1v[K1_CAP], k0v[K0_CAP];
    uint  r0a[R_CAP / 2], r1a[R_CAP / 2], k1a[K1_CAP / 2], k0a[K0_CAP / 2];
#pragma unroll
    for (int k = 0; k < R_CAP; ++k) { r0v[k] = Fr0v[j * R_CAP + k]; r1v[k] = Fr1v[j * R_CAP + k]; }
#pragma unroll
    for (int k = 0; k < R_CAP / 2; ++k) { r0a[k] = Fr0a[j * (R_CAP / 2) + k]; r1a[k] = Fr1a[j * (R_CAP / 2) + k]; }
#pragma unroll
    for (int k = 0; k < K1_CAP; ++k) k1v[k] = Fk1v[j * K1_CAP + k];
#pragma unroll
    for (int k = 0; k < K1_CAP / 2; ++k) k1a[k] = Fk1a[j * (K1_CAP / 2) + k];
#pragma unroll
    for (int k = 0; k < K0_CAP; ++k) k0v[k] = Fk0v[j * K0_CAP + k];
#pragma unroll
    for (int k = 0; k < K0_CAP / 2; ++k) k0a[k] = Fk0a[j * (K0_CAP / 2) + k];

    const int u1 = Fu1[j];
    const float b0 = bias0[j],  d0 = d0r[j];       // module 0: identity
    const float b1 = bias1[u1], d1 = d1r[u1];      // module 1: slot j's unit
    const uint l1off = (uint)(Linv1[j] << 2);      // unit j's h1 slot
    float* o0p = out + j;                          // coalesced stores
    float* o1p = out + 1024 + j;

    int k1m = Fc1[j], k0m = Fc0[j];
#pragma unroll
    for (int s = 32; s >= 1; s >>= 1) {
        int a = __shfl_xor(k1m, s, 64); k1m = a > k1m ? a : k1m;
        int b = __shfl_xor(k0m, s, 64); k0m = b > k0m ? b : k0m;
    }
    k1m = __builtin_amdgcn_readfirstlane((k1m + 3) & ~3);
    k0m = __builtin_amdgcn_readfirstlane((k0m + 1) & ~1);

    ((float*)(smem        ))[j] = 0.f;
    ((float*)(smem +  4096))[j] = 0.f;
    ((float*)(smem +  8192))[j] = 0.f;
    ((float*)(smem + 12288))[j] = 0.f;
    float h0j = 0.f, h1j = 0.f;

    // i = 0: h0(0) only
    STAGE(0)
    ITER(0, 1, 0, 0, 16384u)
    // i = 1: h0(1) + h1(0)  (h1(-1)=0 from zero-init buffer)
    ITER(1, 1, 1, 0, 16384u + 128u)

    for (int t = 2; t < T_STEPS; t += 2) {
        if ((t & 63) == 0) STAGE(t)
        uint uoff = 16384u + (uint)((t & 63) << 7);
        ITER(0, 1, 1, 1, uoff)
        ITER(1, 1, 1, 1, uoff + 128u)
    }
    // i = T: h1(T-1) only, + gather h1(T-2)
    ITER(0, 0, 1, 1, 16384u)
    // epilogue: gather h1(T-1) (written to hbuf1[1] by the tail ITER)
    *o1p = LD(8192u + 4096u + l1off);
}

// ===========================================================================
extern "C" void kernel_launch(void* const* d_in, const int* in_sizes, int n_in,
                              void* d_out, int out_size, void* d_ws, size_t ws_size,
                              hipStream_t stream) {
    const float* u   = (const float*)d_in[0];
    const float* k0w = (const float*)d_in[1];
    const float* r0w = (const float*)d_in[2];
    const float* b0  = (const float*)d_in[3];
    const float* k1w = (const float*)d_in[4];
    const float* r1w = (const float*)d_in[5];
    const float* b1  = (const float*)d_in[6];
    float* out = (float*)d_out;

    char* w = (char*)d_ws;
    // raw
    float* r0vr = (float*)w; w += 1024 * R_CAP * 4;
    uint*  r0ur = (uint*)w;  w += 1024 * R_CAP * 4;
    float* d0r  = (float*)w; w += 1024 * 4;
    float* r1vr = (float*)w; w += 1024 * R_CAP * 4;
    uint*  r1ur = (uint*)w;  w += 1024 * R_CAP * 4;
    float* d1r  = (float*)w; w += 1024 * 4;
    float* k1vr = (float*)w; w += 1024 * K1_CAP * 4;
    uint*  k1ur = (uint*)w;  w += 1024 * K1_CAP * 4;
    int*   c1r  = (int*)w;   w += 1024 * 4;
    float* k0vr = (float*)w; w += 1024 * K0_CAP * 4;
    uint*  k0ur = (uint*)w;  w += 1024 * K0_CAP * 4;
    int*   c0r  = (int*)w;   w += 1024 * 4;
    // G (unpacked)
    uint*  Gr0a = (uint*)w;  w += 1024 * R_CAP * 4;
    float* Gr0v = (float*)w; w += 1024 * R_CAP * 4;
    int*   Gcr0 = (int*)w;   w += 1024 * 4;
    uint*  Gr1a = (uint*)w;  w += 1024 * R_CAP * 4;
    float* Gr1v = (float*)w; w += 1024 * R_CAP * 4;
    int*   Gcr1 = (int*)w;   w += 1024 * 4;
    uint*  Gk1a = (uint*)w;  w += 1024 * K1_CAP * 4;
    float* Gk1v = (float*)w; w += 1024 * K1_CAP * 4;
    uint*  Gk0a = (uint*)w;  w += 1024 * K0_CAP * 4;
    float* Gk0v = (float*)w; w += 1024 * K0_CAP * 4;
    // F (packed)
    float* Fr0v = (float*)w; w += 1024 * R_CAP * 4;
    uint*  Fr0a = (uint*)w;  w += 1024 * (R_CAP / 2) * 4;
    float* Fr1v = (float*)w; w += 1024 * R_CAP * 4;
    uint*  Fr1a = (uint*)w;  w += 1024 * (R_CAP / 2) * 4;
    float* Fk1v = (float*)w; w += 1024 * K1_CAP * 4;
    uint*  Fk1a = (uint*)w;  w += 1024 * (K1_CAP / 2) * 4;
    float* Fk0v = (float*)w; w += 1024 * K0_CAP * 4;
    uint*  Fk0a = (uint*)w;  w += 1024 * (K0_CAP / 2) * 4;
    int*   Fc1  = (int*)w;   w += 1024 * 4;
    int*   Fc0  = (int*)w;   w += 1024 * 4;
    int*   Fu1  = (int*)w;   w += 1024 * 4;
    int*   Linv1 = (int*)w;

    prep_extract<<<16, 256, 0, stream>>>(k0w, r0w, r1w, k1w,
                                         r0vr, r0ur, d0r, r1vr, r1ur, d1r,
                                         k1vr, k1ur, c1r, k0vr, k0ur, c0r);
    prep_slots<<<1, 1024, 0, stream>>>(r0vr, r0ur, r1vr, r1ur,
                                       k1vr, k1ur, c1r, k0vr, k0ur, c0r,
                                       Gr0a, Gr0v, Gcr0, Gr1a, Gr1v, Gcr1,
                                       Gk1a, Gk1v, Fc1, Gk0a, Gk0v, Fc0,
                                       Fu1, Linv1);
    prep_greedy<<<16, 256, 0, stream>>>(Gr0a, Gr0v, Gcr0, Gr1a, Gr1v, Gcr1,
                                        Gk1a, Gk1v, Fc1, Gk0a, Gk0v, Fc0,
                                        Fr0v, Fr0a, Fr1v, Fr1a,
                                        Fk1v, Fk1a, Fk0v, Fk0a);
    reservoir_main<<<1, 1024, 0, stream>>>(u, b0, b1, d0r, d1r,
                                           Fr0v, Fr0a, Fr1v, Fr1a,
                                           Fk1v, Fk1a, Fk0v, Fk0a,
                                           Fc1, Fc0, Fu1, Linv1,
                                           out);
}